// Round 1
// baseline (224.918 us; speedup 1.0000x reference)
//
#include <hip/hip_runtime.h>

#define N_NODES 100000
#define N_EDGES 1600000
#define IN_DIM 128
#define OUT_DIM 32

// -------- kernel 1: support = X @ W  (fp32, memory-bound) --------
// 8 rows per block, 256 threads: thread (r,c) computes support[row0+r][c].
__global__ __launch_bounds__(256) void gemm_support(
    const float* __restrict__ x, const float* __restrict__ w,
    float* __restrict__ support) {
  __shared__ float ws[IN_DIM][OUT_DIM];   // 16 KB
  __shared__ float xs[8][IN_DIM];         // 4 KB
  const int tid = threadIdx.x;

  // stage W
  for (int i = tid; i < IN_DIM * OUT_DIM; i += 256) {
    ws[i / OUT_DIM][i % OUT_DIM] = w[i];
  }
  // stage 8 rows of x (coalesced: consecutive tid -> consecutive k)
  const int row0 = blockIdx.x * 8;
  for (int i = tid; i < 8 * IN_DIM; i += 256) {
    const int r = i / IN_DIM, k = i % IN_DIM;
    const int row = row0 + r;
    xs[r][k] = (row < N_NODES) ? x[(long long)row * IN_DIM + k] : 0.f;
  }
  __syncthreads();

  const int r = tid >> 5;     // 0..7
  const int c = tid & 31;     // 0..31
  const int row = row0 + r;
  if (row >= N_NODES) return;

  float acc = 0.f;
#pragma unroll
  for (int k = 0; k < IN_DIM; ++k) {
    // ws[k][c]: 32 lanes read 32 consecutive floats -> conflict-free
    // xs[r][k]: broadcast within the 32-lane group
    acc = fmaf(xs[r][k], ws[k][c], acc);
  }
  support[(long long)row * OUT_DIM + c] = acc;
}

// -------- kernel 2: out[i] = bias[i % 32] --------
__global__ __launch_bounds__(256) void init_out(
    const float* __restrict__ bias, float* __restrict__ out) {
  const int i = blockIdx.x * 256 + threadIdx.x;
  if (i < N_NODES * OUT_DIM) out[i] = bias[i & (OUT_DIM - 1)];
}

// -------- kernel 3: edge-parallel COO scatter --------
// 32 threads per edge, one per output dim. Coalesced gather of support[col]
// and coalesced atomicAdd into out[row].
__global__ __launch_bounds__(256) void spmm_scatter(
    const int* __restrict__ rows, const int* __restrict__ cols,
    const float* __restrict__ vals, const float* __restrict__ support,
    float* __restrict__ out) {
  const long long gid = (long long)blockIdx.x * 256 + threadIdx.x;
  if (gid >= (long long)N_EDGES * OUT_DIM) return;
  const int e = (int)(gid >> 5);
  const int d = (int)(gid & 31);
  const int r = rows[e];
  const int c = cols[e];
  const float v = vals[e];
  atomicAdd(&out[(long long)r * OUT_DIM + d],
            v * support[(long long)c * OUT_DIM + d]);
}

extern "C" void kernel_launch(void* const* d_in, const int* in_sizes, int n_in,
                              void* d_out, int out_size, void* d_ws, size_t ws_size,
                              hipStream_t stream) {
  const float* x        = (const float*)d_in[0];
  const int*   adj_rows = (const int*)d_in[1];
  const int*   adj_cols = (const int*)d_in[2];
  const float* adj_vals = (const float*)d_in[3];
  const float* weight   = (const float*)d_in[4];
  const float* bias     = (const float*)d_in[5];
  float* out = (float*)d_out;

  // workspace: support [N_NODES, OUT_DIM] fp32 = 12.8 MB
  float* support = (float*)d_ws;

  // 1) support = X @ W
  {
    const int grid = (N_NODES + 7) / 8;
    gemm_support<<<grid, 256, 0, stream>>>(x, weight, support);
  }
  // 2) out = bias (broadcast)
  {
    const int total = N_NODES * OUT_DIM;
    init_out<<<(total + 255) / 256, 256, 0, stream>>>(bias, out);
  }
  // 3) out += A @ support
  {
    const long long total = (long long)N_EDGES * OUT_DIM;
    const int grid = (int)((total + 255) / 256);
    spmm_scatter<<<grid, 256, 0, stream>>>(adj_rows, adj_cols, adj_vals,
                                           support, out);
  }
}